// Round 13
// baseline (161.338 us; speedup 1.0000x reference)
//
#include <hip/hip_runtime.h>

// Problem constants
#define BB   4
#define SEQ  2048
#define EMB  512
#define NH   8
#define HD   64
// SCALE = HD^-0.5 = 0.125; folded with log2(e) into Q at qkv epilogue:
#define QSCALE 0.18033688011f   // 0.125 * log2(e)

typedef __bf16 bf16x8 __attribute__((ext_vector_type(8)));
typedef float  f32x4  __attribute__((ext_vector_type(4)));

__device__ __forceinline__ short f2bf(float f) {
  union { float f; unsigned u; } v; v.f = f;
  unsigned r = v.u + 0x7fffu + ((v.u >> 16) & 1u);   // RNE
  return (short)(r >> 16);
}

// packed fp32x2 -> bf16x2 (RNE), hardware on gfx950
__device__ __forceinline__ unsigned pk_bf16(float a, float b) {
#if __has_builtin(__builtin_amdgcn_cvt_pk_bf16_f32)
  typedef __bf16 bf16v2 __attribute__((ext_vector_type(2)));
  union { bf16v2 v; unsigned u; } cv;
  cv.v = __builtin_amdgcn_cvt_pk_bf16_f32(a, b);
  return cv.u;
#else
  return (unsigned)(unsigned short)f2bf(a) | ((unsigned)(unsigned short)f2bf(b) << 16);
#endif
}

__device__ __forceinline__ float fexp2(float x) {
#if __has_builtin(__builtin_amdgcn_exp2f)
  return __builtin_amdgcn_exp2f(x);
#else
  return exp2f(x);
#endif
}

__device__ __forceinline__ void gl_lds16(const void* g, void* l) {
  __builtin_amdgcn_global_load_lds(
      (const __attribute__((address_space(1))) unsigned int*)g,
      (__attribute__((address_space(3))) unsigned int*)l, 16, 0, 0);
}

// quad-axis redistribution for P: (a,b) = (even-kt, odd-kt) packed pair.
// After the two swaps (gfx950 VALU cross-lane, no LDS pipe) the words land in
// exactly the PV A-fragment layout (verified round 4: absmax unchanged, conflicts 0).
__device__ __forceinline__ void quad_redist(unsigned &a, unsigned &b) {
  asm volatile("v_permlane32_swap_b32 %0, %1" : "+v"(a), "+v"(b));
  asm volatile("v_permlane16_swap_b32 %0, %1" : "+v"(a), "+v"(b));
}

// ---------------------------------------------------------------- fused casts
// x: 1048576 float4 groups; w_qkv: 196608; w_out: 65536. total 1310720 -> 5120 blocks
__global__ __launch_bounds__(256) void cast_all(const float* __restrict__ x,
                                                const float* __restrict__ wq,
                                                const float* __restrict__ wo,
                                                short* __restrict__ xb,
                                                short* __restrict__ wqb,
                                                short* __restrict__ wob) {
  int i = blockIdx.x * 256 + threadIdx.x;
  const float* src; short* dst; int off;
  if (i < 1048576)      { src = x;  dst = xb;  off = i; }
  else if (i < 1245184) { src = wq; dst = wqb; off = i - 1048576; }
  else                  { src = wo; dst = wob; off = i - 1245184; }
  float4 v = ((const float4*)src)[off];
  uint2 o; o.x = pk_bf16(v.x, v.y); o.y = pk_bf16(v.z, v.w);
  *(uint2*)&dst[off * 4] = o;
}

// ---------------------------------------------------------------- QKV projection
// v4 (round-10 best): 512 threads (8 waves as 4m x 2f, wave tile 32x64, acc[2][4]);
// 128x128 tile, BK=32 double-buffered, one gl_lds16 per operand per K-step,
// one barrier per step. LDS 32KB; (512,6) -> 3 blocks/CU (grid 768 = 3x256).
// Swizzle: store chunk c of row holds source k-chunk c^((row>>1)&3); read chunk
// quad^((col>>1)&3); read rows = 16k+col so (row>>1)&3 == (col>>1)&3 -> recovers quad.
__global__ __launch_bounds__(512, 6) void qkv_gemm(const short* __restrict__ A,
                                                   const short* __restrict__ W,
                                                   const float* __restrict__ bias,
                                                   short* __restrict__ qo,
                                                   short* __restrict__ ko,
                                                   short* __restrict__ vto) {
  __shared__ __align__(16) short As0[128 * 32];
  __shared__ __align__(16) short Bs0[128 * 32];
  __shared__ __align__(16) short As1[128 * 32];
  __shared__ __align__(16) short Bs1[128 * 32];
  const int tid  = threadIdx.x;
  const int lane = tid & 63, wave = tid >> 6;
  const int wm = wave >> 1, wf = wave & 1;
  const int col = lane & 15, quad = lane >> 4;
  const int m0 = blockIdx.x * 128, f0 = blockIdx.y * 128;

  // staging: slot = tid (512 slots = 128 rows x 4 chunks)
  const int row = tid >> 2;
  const int cb  = (tid & 3) ^ ((tid >> 3) & 3);
  const short* aSrc = A + (size_t)(m0 + row) * 512 + cb * 8;
  const short* wSrc = W + (size_t)(f0 + row) * 512 + cb * 8;

  // fragment LDS element offsets (row*32 + readchunk*8)
  const int rc = (quad ^ ((col >> 1) & 3)) * 8;
  int aOff[2], bOff[4];
#pragma unroll
  for (int i = 0; i < 2; ++i) aOff[i] = (wm * 32 + i * 16 + col) * 32 + rc;
#pragma unroll
  for (int j = 0; j < 4; ++j) bOff[j] = (wf * 64 + j * 16 + col) * 32 + rc;

  f32x4 acc[2][4];
#pragma unroll
  for (int i = 0; i < 2; ++i)
#pragma unroll
    for (int j = 0; j < 4; ++j)
#pragma unroll
      for (int r = 0; r < 4; ++r) acc[i][j][r] = 0.f;

#define QSTAGE(BUFA, BUFB, KS)                                        \
  {                                                                   \
    gl_lds16(aSrc + (KS) * 32, (char*)(BUFA) + wave * 1024);          \
    gl_lds16(wSrc + (KS) * 32, (char*)(BUFB) + wave * 1024);          \
  }

  auto qcompute = [&](const short* As, const short* Bs) {
    bf16x8 af[2], bw[4];
#pragma unroll
    for (int i = 0; i < 2; ++i) af[i] = *(const bf16x8*)&As[aOff[i]];
#pragma unroll
    for (int j = 0; j < 4; ++j) bw[j] = *(const bf16x8*)&Bs[bOff[j]];
#pragma unroll
    for (int i = 0; i < 2; ++i)
#pragma unroll
      for (int j = 0; j < 4; ++j)
        acc[i][j] = __builtin_amdgcn_mfma_f32_16x16x32_bf16(af[i], bw[j], acc[i][j], 0, 0, 0);
  };

  // prologue
  QSTAGE(As0, Bs0, 0);
  __syncthreads();
  for (int t = 0; t < 16; t += 2) {
    QSTAGE(As1, Bs1, t + 1);          // t+1 <= 15 always
    qcompute(As0, Bs0);
    __syncthreads();                  // drains t+1 loads (flew during compute)
    QSTAGE(As0, Bs0, (t + 2) & 15);   // last iter wraps to 0 (harmless re-read, avoids OOB)
    qcompute(As1, Bs1);
    __syncthreads();
  }
#undef QSTAGE

  // epilogue: C/D layout row = quad*4+r, col = lane&15
#pragma unroll
  for (int j = 0; j < 4; ++j) {
    const int f = f0 + wf * 64 + j * 16 + col;
    const float bv = bias[f];
    const int sIdx = f >> 9;          // 0=Q 1=K 2=V (uniform per wave: 64-wide span)
    const int h = (f >> 6) & 7;
    const int d = f & 63;
#pragma unroll
    for (int i = 0; i < 2; ++i) {
      const int mbase = m0 + wm * 32 + i * 16 + quad * 4;
      const int b = mbase >> 11;
      const int n = mbase & 2047;
      const size_t bh = (size_t)(b * NH + h);
      if (sIdx == 2) {
        uint2 pk;
        pk.x = pk_bf16(acc[i][j][0] + bv, acc[i][j][1] + bv);
        pk.y = pk_bf16(acc[i][j][2] + bv, acc[i][j][3] + bv);
        *(uint2*)&vto[(bh * HD + d) * SEQ + n] = pk;     // V^T: (bh, d, n)
      } else if (sIdx == 0) {
#pragma unroll
        for (int r = 0; r < 4; ++r)
          qo[(bh * SEQ + n + r) * HD + d] = f2bf((acc[i][j][r] + bv) * QSCALE);
      } else {
#pragma unroll
        for (int r = 0; r < 4; ++r)
          ko[(bh * SEQ + n + r) * HD + d] = f2bf(acc[i][j][r] + bv);
      }
    }
  }
}

// ---------------------------------------------------------------- flash attention v8: KVBLK=128
// grid = 512 x 512 threads: bh = blk&31, qtile = blk>>5 (128 q/block, 8 waves x 16 q)
// v8 change: KV tile 64 -> 128 — HALVES the barrier-period count (32 -> 16).
//   Round-12 analysis: period = 4330cy, LDS-pipe floor = 3072cy (71%); the ~17us
//   above the 41us LDS floor is per-period overhead (barrier + slowest wave).
//   Same LDS bytes per key, 2x fatter periods. LDS 64KB, still 2 blocks/CU.
// K: [128][64] XOR-swizzled (8 chunks, c^(row&7)); V^T: [64][128] XOR-swizzled
//   (16 chunks, c^(row&15); read chunk (ks2*4+quad)^col with row&15==col).
// P: in-register redistribution (permlane16/32_swap): pf[m] from kt {2m,2m+1}.
// S^T operand-swap; fixed-max softmax (exp2, scale pre-folded into Q).
__global__ __launch_bounds__(512) void attn_kernel(const short* __restrict__ q,
                                                   const short* __restrict__ k,
                                                   const short* __restrict__ vt,
                                                   short* __restrict__ o) {
  __shared__ __align__(16) short Ks0[128 * 64];      // 16KB
  __shared__ __align__(16) short Vs0[64 * 128];      // 16KB
  __shared__ __align__(16) short Ks1[128 * 64];
  __shared__ __align__(16) short Vs1[64 * 128];

  const int tid  = threadIdx.x;
  const int lane = tid & 63, wave = tid >> 6;
  const int col = lane & 15, quad = lane >> 4;
  const int bh = blockIdx.x & 31;
  const int q0 = (blockIdx.x >> 5) * 128;
  const size_t bhBase = (size_t)bh * SEQ * HD;

  // Q fragments (B-operand): lane holds Q'[q=col][d = ks*32 + quad*8 + j]
  bf16x8 qf[2];
#pragma unroll
  for (int ks = 0; ks < 2; ++ks)
    qf[ks] = *(const bf16x8*)&q[bhBase +
        (size_t)(q0 + wave * 16 + col) * HD + ks * 32 + quad * 8];

  // staging: 2 issues per operand per tile (1024 slots each)
  // K: slot -> row = slot>>3 (0..127), chunk = slot&7, src chunk = (slot&7)^(row&7)
  // V: slot -> row = slot>>4 (0..63),  chunk = slot&15, src chunk = (slot&15)^(row&15)
  const short* ksrc[2]; const short* vsrc[2];
#pragma unroll
  for (int it = 0; it < 2; ++it) {
    int kslot = it * 512 + tid;
    int krow  = kslot >> 3;
    int kcb   = (kslot & 7) ^ (krow & 7);
    ksrc[it] = k + bhBase + (size_t)krow * HD + kcb * 8;
    int vslot = it * 512 + tid;
    int vrow  = vslot >> 4;
    int vcb   = (vslot & 15) ^ (vrow & 15);
    vsrc[it] = vt + bhBase + (size_t)vrow * SEQ + vcb * 8;
  }

  f32x4 oacc[4];
#pragma unroll
  for (int nt = 0; nt < 4; ++nt)
#pragma unroll
    for (int r = 0; r < 4; ++r) oacc[nt][r] = 0.f;
  float lsum = 0.f;

  auto compute = [&](const short* KB, const short* VB) {
    // S^T = K Q'^T : C[m=key][n=q]; lane holds S^T[key=kt*16+quad*4+r][q=col]
    f32x4 sacc[8];
#pragma unroll
    for (int kt = 0; kt < 8; ++kt)
#pragma unroll
      for (int r = 0; r < 4; ++r) sacc[kt][r] = 0.f;
#pragma unroll
    for (int ks = 0; ks < 2; ++ks)
#pragma unroll
      for (int kt = 0; kt < 8; ++kt) {
        bf16x8 kf = *(const bf16x8*)&KB[(kt * 16 + col) * 64 +
                                        (((ks * 4 + quad) ^ (col & 7)) * 8)];
        sacc[kt] = __builtin_amdgcn_mfma_f32_16x16x32_bf16(kf, qf[ks], sacc[kt], 0, 0, 0);
      }

    // p = exp2(s') (scale pre-folded into Q'), partial row-sums, pack pairs
    unsigned u[8][2];
#pragma unroll
    for (int kt = 0; kt < 8; ++kt) {
      float p0 = fexp2(sacc[kt][0]);
      float p1 = fexp2(sacc[kt][1]);
      float p2 = fexp2(sacc[kt][2]);
      float p3 = fexp2(sacc[kt][3]);
      lsum += (p0 + p1) + (p2 + p3);
      u[kt][0] = pk_bf16(p0, p1);   // keys kt*16+quad*4+{0,1}
      u[kt][1] = pk_bf16(p2, p3);   // keys kt*16+quad*4+{2,3}
    }

    // in-register quad redistribution -> PV A-fragments
    // pf[m] elem j = P[q=col][key = m*32 + quad*8 + j]  (from kt pair {2m,2m+1})
    union { unsigned w[4]; bf16x8 v; } pf[4];
#pragma unroll
    for (int m = 0; m < 4; ++m) {
      unsigned a, b;
      a = u[2 * m][0]; b = u[2 * m + 1][0]; quad_redist(a, b); pf[m].w[0] = a; pf[m].w[2] = b;
      a = u[2 * m][1]; b = u[2 * m + 1][1]; quad_redist(a, b); pf[m].w[1] = a; pf[m].w[3] = b;
    }

    // O += P V   (A = P[q][key] in registers, B = V^T[d][key] from LDS)
    // V row = nt*16+col (d), chunk = (ks2*4+quad)^col -> source chunk ks2*4+quad
#pragma unroll
    for (int ks2 = 0; ks2 < 4; ++ks2)
#pragma unroll
      for (int nt = 0; nt < 4; ++nt) {
        bf16x8 vf = *(const bf16x8*)&VB[(nt * 16 + col) * 128 +
                                        (((ks2 * 4 + quad) ^ col) * 8)];
        oacc[nt] = __builtin_amdgcn_mfma_f32_16x16x32_bf16(pf[ks2].v, vf, oacc[nt], 0, 0, 0);
      }
  };

#define STAGE(KBUF, VBUF)                                              \
  {                                                                    \
    gl_lds16(ksrc[0], (char*)(KBUF) + wave * 1024);                    \
    gl_lds16(ksrc[1], (char*)(KBUF) + 8192 + wave * 1024);             \
    gl_lds16(vsrc[0], (char*)(VBUF) + wave * 1024);                    \
    gl_lds16(vsrc[1], (char*)(VBUF) + 8192 + wave * 1024);             \
    ksrc[0] += 128 * HD; ksrc[1] += 128 * HD;                          \
    vsrc[0] += 128;      vsrc[1] += 128;                               \
  }

  // prologue: stage tile 0
  STAGE(Ks0, Vs0);
  __syncthreads();

  for (int t = 0; t < 16; t += 2) {
    // stage tile t+1 into buf1; compute tile t from buf0
    STAGE(Ks1, Vs1);
    compute(Ks0, Vs0);
    __syncthreads();                 // drains t+1 loads (flew during compute)
    // stage tile t+2 into buf0; compute tile t+1 from buf1
    // (final iteration prefetches one tile past the end — lands in the
    //  adjacent workspace arrays, in-bounds of d_ws, never consumed)
    STAGE(Ks0, Vs0);
    compute(Ks1, Vs1);
    __syncthreads();
  }
#undef STAGE

  // final row-sum reduce across quads (lanes sharing col hold partials)
  lsum += __shfl_xor(lsum, 16);
  lsum += __shfl_xor(lsum, 32);

  const int b = bh >> 3, h = bh & 7;
#pragma unroll
  for (int r = 0; r < 4; ++r) {
    const float rl = 1.0f / __shfl(lsum, quad * 4 + r);  // sum for q=quad*4+r lives at lane col==q
    const int n = q0 + wave * 16 + quad * 4 + r;
#pragma unroll
    for (int nt = 0; nt < 4; ++nt)
      o[((size_t)(b * SEQ + n)) * EMB + h * HD + nt * 16 + col] = f2bf(oacc[nt][r] * rl);
  }
}

// ---------------------------------------------------------------- out projection
// v4 (round-10 best): 64x128 tile, BK=32 dbuf, 512 threads (8 waves as 2m x 4f,
// wave tile 32x32, acc[2][2]); grid (128,4) = 512 blocks = 2/CU, LDS 24KB.
// A staged by waves 0-3 (64x32 = 4KB), W by all 8 waves (128x32 = 8KB).
__global__ __launch_bounds__(512, 4) void proj_gemm(const short* __restrict__ A,
                                                    const short* __restrict__ W,
                                                    const float* __restrict__ bias,
                                                    float* __restrict__ out) {
  __shared__ __align__(16) short As0[64 * 32];
  __shared__ __align__(16) short Bs0[128 * 32];
  __shared__ __align__(16) short As1[64 * 32];
  __shared__ __align__(16) short Bs1[128 * 32];
  const int tid  = threadIdx.x;
  const int lane = tid & 63, wave = tid >> 6;
  const int wm = wave >> 2, wf = wave & 3;
  const int col = lane & 15, quad = lane >> 4;
  const int m0 = blockIdx.x * 64, f0 = blockIdx.y * 128;

  // A staging slot (waves 0-3 only): aslot = tid&255 -> 64 rows x 4 chunks
  const int aslot = tid & 255;
  const int arow = aslot >> 2, acb = (aslot & 3) ^ ((aslot >> 3) & 3);
  const short* aSrc = A + (size_t)(m0 + arow) * 512 + acb * 8;
  // W staging slot (all 8 waves): 128 rows x 4 chunks
  const int wrow = tid >> 2, wcb = (tid & 3) ^ ((tid >> 3) & 3);
  const short* wSrc = W + (size_t)(f0 + wrow) * 512 + wcb * 8;

  const int rc = (quad ^ ((col >> 1) & 3)) * 8;
  int aOff[2], bOff[2];
#pragma unroll
  for (int i = 0; i < 2; ++i) aOff[i] = (wm * 32 + i * 16 + col) * 32 + rc;
#pragma unroll
  for (int j = 0; j < 2; ++j) bOff[j] = (wf * 32 + j * 16 + col) * 32 + rc;

  f32x4 acc[2][2];
#pragma unroll
  for (int i = 0; i < 2; ++i)
#pragma unroll
    for (int j = 0; j < 2; ++j)
#pragma unroll
      for (int r = 0; r < 4; ++r) acc[i][j][r] = 0.f;

#define PSTAGE(BUFA, BUFB, KS)                                        \
  {                                                                   \
    if (wave < 4) gl_lds16(aSrc + (KS) * 32, (char*)(BUFA) + wave * 1024); \
    gl_lds16(wSrc + (KS) * 32, (char*)(BUFB) + wave * 1024);          \
  }

  auto pcompute = [&](const short* As, const short* Bs) {
    bf16x8 af[2], bw[2];
#pragma unroll
    for (int i = 0; i < 2; ++i) af[i] = *(const bf16x8*)&As[aOff[i]];
#pragma unroll
    for (int j = 0; j < 2; ++j) bw[j] = *(const bf16x8*)&Bs[bOff[j]];
#pragma unroll
    for (int i = 0; i < 2; ++i)
#pragma unroll
      for (int j = 0; j < 2; ++j)
        acc[i][j] = __builtin_amdgcn_mfma_f32_16x16x32_bf16(af[i], bw[j], acc[i][j], 0, 0, 0);
  };

  PSTAGE(As0, Bs0, 0);
  __syncthreads();
  for (int t = 0; t < 16; t += 2) {
    PSTAGE(As1, Bs1, t + 1);
    pcompute(As0, Bs0);
    __syncthreads();
    PSTAGE(As0, Bs0, (t + 2) & 15);   // wrap on last iter (harmless, avoids OOB)
    pcompute(As1, Bs1);
    __syncthreads();
  }
#undef PSTAGE

#pragma unroll
  for (int j = 0; j < 2; ++j) {
    const int f = f0 + wf * 32 + j * 16 + col;
    const float bv = bias[f];
#pragma unroll
    for (int i = 0; i < 2; ++i) {
      const int mbase = m0 + wm * 32 + i * 16 + quad * 4;
#pragma unroll
      for (int r = 0; r < 4; ++r)
        out[(size_t)(mbase + r) * 512 + f] = acc[i][j][r] + bv;
    }
  }
}

// ---------------------------------------------------------------- launch
extern "C" void kernel_launch(void* const* d_in, const int* in_sizes, int n_in,
                              void* d_out, int out_size, void* d_ws, size_t ws_size,
                              hipStream_t stream) {
  (void)in_sizes; (void)n_in; (void)out_size; (void)ws_size;
  const float* x     = (const float*)d_in[0];
  const float* w_qkv = (const float*)d_in[1];
  const float* b_qkv = (const float*)d_in[2];
  const float* w_out = (const float*)d_in[3];
  const float* b_out = (const float*)d_in[4];
  float* out = (float*)d_out;

  char* ws = (char*)d_ws;
  short* xb    = (short*)(ws + 0);         // 8,388,608
  short* wqkvb = (short*)(ws + 8388608);   // 1,572,864
  short* woutb = (short*)(ws + 9961472);   //   524,288
  short* qb    = (short*)(ws + 10485760);  // 8,388,608  (b,h,n,d)  pre-scaled by QSCALE
  short* kb    = (short*)(ws + 18874368);  // 8,388,608  (b,h,n,d)
  short* vtb   = (short*)(ws + 27262976);  // 8,388,608  (b,h,d,n)
  short* ob    = (short*)(ws + 35651584);  // 8,388,608  (b,n,e)

  cast_all<<<5120, 256, 0, stream>>>(x, w_qkv, w_out, xb, wqkvb, woutb);
  qkv_gemm<<<dim3(64, 12), 512, 0, stream>>>(xb, wqkvb, b_qkv, qb, kb, vtb);
  attn_kernel<<<512, 512, 0, stream>>>(qb, kb, vtb, ob);
  proj_gemm<<<dim3(128, 4), 512, 0, stream>>>(ob, woutb, b_out, out);
}

// Round 14
// 155.801 us; speedup vs baseline: 1.0355x; 1.0355x over previous
//
#include <hip/hip_runtime.h>

// Problem constants
#define BB   4
#define SEQ  2048
#define EMB  512
#define NH   8
#define HD   64
// SCALE = HD^-0.5 = 0.125; folded with log2(e) into Q at qkv epilogue:
#define QSCALE 0.18033688011f   // 0.125 * log2(e)

typedef __bf16 bf16x8 __attribute__((ext_vector_type(8)));
typedef float  f32x4  __attribute__((ext_vector_type(4)));
typedef float  f32x16 __attribute__((ext_vector_type(16)));

__device__ __forceinline__ short f2bf(float f) {
  union { float f; unsigned u; } v; v.f = f;
  unsigned r = v.u + 0x7fffu + ((v.u >> 16) & 1u);   // RNE
  return (short)(r >> 16);
}

// packed fp32x2 -> bf16x2 (RNE), hardware on gfx950
__device__ __forceinline__ unsigned pk_bf16(float a, float b) {
#if __has_builtin(__builtin_amdgcn_cvt_pk_bf16_f32)
  typedef __bf16 bf16v2 __attribute__((ext_vector_type(2)));
  union { bf16v2 v; unsigned u; } cv;
  cv.v = __builtin_amdgcn_cvt_pk_bf16_f32(a, b);
  return cv.u;
#else
  return (unsigned)(unsigned short)f2bf(a) | ((unsigned)(unsigned short)f2bf(b) << 16);
#endif
}

__device__ __forceinline__ float fexp2(float x) {
#if __has_builtin(__builtin_amdgcn_exp2f)
  return __builtin_amdgcn_exp2f(x);
#else
  return exp2f(x);
#endif
}

__device__ __forceinline__ void gl_lds16(const void* g, void* l) {
  __builtin_amdgcn_global_load_lds(
      (const __attribute__((address_space(1))) unsigned int*)g,
      (__attribute__((address_space(3))) unsigned int*)l, 16, 0, 0);
}

// single-instruction 32-lane-half exchange:
// a' = {a_low, b_low(from lanes+32 view)} ... precisely:
//   a_new[l<32]=a[l], a_new[l>=32]=b[l-32]; b_new[l<32]=a[l+32], b_new[l>=32]=b[l]
__device__ __forceinline__ void swap32(unsigned &a, unsigned &b) {
  asm volatile("v_permlane32_swap_b32 %0, %1" : "+v"(a), "+v"(b));
}

// ---------------------------------------------------------------- fused casts
// x: 1048576 float4 groups; w_qkv: 196608; w_out: 65536. total 1310720 -> 5120 blocks
__global__ __launch_bounds__(256) void cast_all(const float* __restrict__ x,
                                                const float* __restrict__ wq,
                                                const float* __restrict__ wo,
                                                short* __restrict__ xb,
                                                short* __restrict__ wqb,
                                                short* __restrict__ wob) {
  int i = blockIdx.x * 256 + threadIdx.x;
  const float* src; short* dst; int off;
  if (i < 1048576)      { src = x;  dst = xb;  off = i; }
  else if (i < 1245184) { src = wq; dst = wqb; off = i - 1048576; }
  else                  { src = wo; dst = wob; off = i - 1245184; }
  float4 v = ((const float4*)src)[off];
  uint2 o; o.x = pk_bf16(v.x, v.y); o.y = pk_bf16(v.z, v.w);
  *(uint2*)&dst[off * 4] = o;
}

// ---------------------------------------------------------------- QKV projection
// v4 (round-10 best): 512 threads (8 waves as 4m x 2f, wave tile 32x64, acc[2][4]);
// 128x128 tile, BK=32 double-buffered, one gl_lds16 per operand per K-step,
// one barrier per step. LDS 32KB; (512,6) -> 3 blocks/CU (grid 768 = 3x256).
__global__ __launch_bounds__(512, 6) void qkv_gemm(const short* __restrict__ A,
                                                   const short* __restrict__ W,
                                                   const float* __restrict__ bias,
                                                   short* __restrict__ qo,
                                                   short* __restrict__ ko,
                                                   short* __restrict__ vto) {
  __shared__ __align__(16) short As0[128 * 32];
  __shared__ __align__(16) short Bs0[128 * 32];
  __shared__ __align__(16) short As1[128 * 32];
  __shared__ __align__(16) short Bs1[128 * 32];
  const int tid  = threadIdx.x;
  const int lane = tid & 63, wave = tid >> 6;
  const int wm = wave >> 1, wf = wave & 1;
  const int col = lane & 15, quad = lane >> 4;
  const int m0 = blockIdx.x * 128, f0 = blockIdx.y * 128;

  const int row = tid >> 2;
  const int cb  = (tid & 3) ^ ((tid >> 3) & 3);
  const short* aSrc = A + (size_t)(m0 + row) * 512 + cb * 8;
  const short* wSrc = W + (size_t)(f0 + row) * 512 + cb * 8;

  const int rc = (quad ^ ((col >> 1) & 3)) * 8;
  int aOff[2], bOff[4];
#pragma unroll
  for (int i = 0; i < 2; ++i) aOff[i] = (wm * 32 + i * 16 + col) * 32 + rc;
#pragma unroll
  for (int j = 0; j < 4; ++j) bOff[j] = (wf * 64 + j * 16 + col) * 32 + rc;

  f32x4 acc[2][4];
#pragma unroll
  for (int i = 0; i < 2; ++i)
#pragma unroll
    for (int j = 0; j < 4; ++j)
#pragma unroll
      for (int r = 0; r < 4; ++r) acc[i][j][r] = 0.f;

#define QSTAGE(BUFA, BUFB, KS)                                        \
  {                                                                   \
    gl_lds16(aSrc + (KS) * 32, (char*)(BUFA) + wave * 1024);          \
    gl_lds16(wSrc + (KS) * 32, (char*)(BUFB) + wave * 1024);          \
  }

  auto qcompute = [&](const short* As, const short* Bs) {
    bf16x8 af[2], bw[4];
#pragma unroll
    for (int i = 0; i < 2; ++i) af[i] = *(const bf16x8*)&As[aOff[i]];
#pragma unroll
    for (int j = 0; j < 4; ++j) bw[j] = *(const bf16x8*)&Bs[bOff[j]];
#pragma unroll
    for (int i = 0; i < 2; ++i)
#pragma unroll
      for (int j = 0; j < 4; ++j)
        acc[i][j] = __builtin_amdgcn_mfma_f32_16x16x32_bf16(af[i], bw[j], acc[i][j], 0, 0, 0);
  };

  QSTAGE(As0, Bs0, 0);
  __syncthreads();
  for (int t = 0; t < 16; t += 2) {
    QSTAGE(As1, Bs1, t + 1);
    qcompute(As0, Bs0);
    __syncthreads();
    QSTAGE(As0, Bs0, (t + 2) & 15);   // last iter wraps to 0 (harmless, avoids OOB)
    qcompute(As1, Bs1);
    __syncthreads();
  }
#undef QSTAGE

#pragma unroll
  for (int j = 0; j < 4; ++j) {
    const int f = f0 + wf * 64 + j * 16 + col;
    const float bv = bias[f];
    const int sIdx = f >> 9;
    const int h = (f >> 6) & 7;
    const int d = f & 63;
#pragma unroll
    for (int i = 0; i < 2; ++i) {
      const int mbase = m0 + wm * 32 + i * 16 + quad * 4;
      const int b = mbase >> 11;
      const int n = mbase & 2047;
      const size_t bh = (size_t)(b * NH + h);
      if (sIdx == 2) {
        uint2 pk;
        pk.x = pk_bf16(acc[i][j][0] + bv, acc[i][j][1] + bv);
        pk.y = pk_bf16(acc[i][j][2] + bv, acc[i][j][3] + bv);
        *(uint2*)&vto[(bh * HD + d) * SEQ + n] = pk;     // V^T: (bh, d, n)
      } else if (sIdx == 0) {
#pragma unroll
        for (int r = 0; r < 4; ++r)
          qo[(bh * SEQ + n + r) * HD + d] = f2bf((acc[i][j][r] + bv) * QSCALE);
      } else {
#pragma unroll
        for (int r = 0; r < 4; ++r)
          ko[(bh * SEQ + n + r) * HD + d] = f2bf(acc[i][j][r] + bv);
      }
    }
  }
}

// ---------------------------------------------------------------- flash attention v9: 32x32 MFMA
// grid = 512 x 512 threads: bh = blk&31, qtile = blk>>5 (128 q/block).
// Waves = (qg 0..3) x (kh 0..1): each wave owns 32 q-rows and HALF the keys of
// every 64-key tile. mfma_f32_32x32x16_bf16 gives 2x FLOP per LDS byte: per
// wave-tile only 4 K-frags + 4 V-frags (8 b128, was 16) -> LDS-pipe floor halves.
// Fixed-max softmax -> key-split waves are fully independent; one f32 merge via
// retired LDS at the end (lane-rotated layout, conflict-free).
// Fragment layouts: A[row=l&31][k=8*(l>>5)+j], B[k=8*(l>>5)+j][col=l&31],
// C/D[row=(r&3)+8*(r>>2)+4*(l>>5)][col=l&31] (verified m74/m101).
// P redistribution: S^T C-layout -> PV A-layout mismatch is only across the
// lane>=32 axis: ONE permlane32_swap per word-pair (derivation checked per-key).
__global__ __launch_bounds__(512, 4) void attn_kernel(const short* __restrict__ q,
                                                      const short* __restrict__ k,
                                                      const short* __restrict__ vt,
                                                      short* __restrict__ o) {
  __shared__ __align__(16) short KV[4][64 * 64];   // [0]=K0 [1]=V0 [2]=K1 [3]=V1; 32KB f32 merge at end
  __shared__ float Ls[4][32];

  const int tid  = threadIdx.x;
  const int lane = tid & 63, wave = tid >> 6;
  const int l31 = lane & 31, g = lane >> 5;
  const int qg = wave >> 1, kh = wave & 1;
  const int bh = blockIdx.x & 31;
  const int q0 = (blockIdx.x >> 5) * 128;
  const size_t bhBase = (size_t)bh * SEQ * HD;

  // Q B-fragments: qf[ks] = Q'[q = q0+qg*32+l31][d = ks*16 + g*8 .. +7]
  bf16x8 qf[4];
#pragma unroll
  for (int ks = 0; ks < 4; ++ks)
    qf[ks] = *(const bf16x8*)&q[bhBase +
        (size_t)(q0 + qg * 32 + l31) * HD + ks * 16 + g * 8];

  // staging (round-4 pattern, verbatim): 512 thr x 16B = one 64x64 tile per issue
  const int row = tid >> 3, cb = (tid & 7) ^ (row & 7);
  const short* ksrc = k  + bhBase + (size_t)row * HD  + cb * 8;
  const short* vsrc = vt + bhBase + (size_t)row * SEQ + cb * 8;
  char* const ldsK0 = (char*)KV[0] + wave * 1024;
  char* const ldsV0 = (char*)KV[1] + wave * 1024;
  char* const ldsK1 = (char*)KV[2] + wave * 1024;
  char* const ldsV1 = (char*)KV[3] + wave * 1024;

  f32x16 oacc[2];
#pragma unroll
  for (int nt = 0; nt < 2; ++nt)
#pragma unroll
    for (int r = 0; r < 16; ++r) oacc[nt][r] = 0.f;
  float lsum = 0.f;

  const int krow = kh * 32 + l31;   // K LDS row this wave reads
  const int kx   = krow & 7;

  auto compute = [&](const short* KB, const short* VB) {
    // S^T[key 32][q 32] = K . Q'^T over d=64 (4 slices of 16)
    f32x16 sacc;
#pragma unroll
    for (int r = 0; r < 16; ++r) sacc[r] = 0.f;
#pragma unroll
    for (int ks = 0; ks < 4; ++ks) {
      bf16x8 kf = *(const bf16x8*)&KB[krow * 64 + (((ks * 2 + g) ^ kx) * 8)];
      sacc = __builtin_amdgcn_mfma_f32_32x32x16_bf16(kf, qf[ks], sacc, 0, 0, 0);
    }
    // p = exp2(s'); lane holds P[key=(r&3)+8*(r>>2)+4g][q=l31]
    unsigned u[4][2];    // u[hi] = keys 8*hi+4g+{0,1},{2,3} packed bf16x2
#pragma unroll
    for (int hi = 0; hi < 4; ++hi) {
      float p0 = fexp2(sacc[4 * hi + 0]);
      float p1 = fexp2(sacc[4 * hi + 1]);
      float p2 = fexp2(sacc[4 * hi + 2]);
      float p3 = fexp2(sacc[4 * hi + 3]);
      lsum += (p0 + p1) + (p2 + p3);
      u[hi][0] = pk_bf16(p0, p1);
      u[hi][1] = pk_bf16(p2, p3);
    }
    // -> PV A-frags: pf[km] word j = P[q=l31][key = km*16 + 8g + 2j..]
    union { unsigned w[4]; bf16x8 v; } pf[2];
    {
      unsigned a, b;
      a = u[0][0]; b = u[1][0]; swap32(a, b); pf[0].w[0] = a; pf[0].w[2] = b;
      a = u[0][1]; b = u[1][1]; swap32(a, b); pf[0].w[1] = a; pf[0].w[3] = b;
      a = u[2][0]; b = u[3][0]; swap32(a, b); pf[1].w[0] = a; pf[1].w[2] = b;
      a = u[2][1]; b = u[3][1]; swap32(a, b); pf[1].w[1] = a; pf[1].w[3] = b;
    }
    // O[32q][64d] += P[32q][32k] . V[32k][64d]   (V from V^T LDS [d][key])
#pragma unroll
    for (int km = 0; km < 2; ++km)
#pragma unroll
      for (int nt = 0; nt < 2; ++nt) {
        const int vrow = nt * 32 + l31;
        bf16x8 vf = *(const bf16x8*)&VB[vrow * 64 +
                                        (((kh * 4 + km * 2 + g) ^ (vrow & 7)) * 8)];
        oacc[nt] = __builtin_amdgcn_mfma_f32_32x32x16_bf16(pf[km].v, vf, oacc[nt], 0, 0, 0);
      }
  };

  // prologue: stage tile 0
  gl_lds16(ksrc, ldsK0); gl_lds16(vsrc, ldsV0);
  ksrc += 64 * HD; vsrc += 64;
  __syncthreads();

  for (int t = 0; t < 32; t += 2) {
    gl_lds16(ksrc, ldsK1); gl_lds16(vsrc, ldsV1);
    ksrc += 64 * HD; vsrc += 64;
    compute((const short*)KV[0], (const short*)KV[1]);
    __syncthreads();
    // (final iteration prefetches one tile past the end — lands in the adjacent
    //  workspace arrays, in-bounds of d_ws, drained by the final barrier)
    gl_lds16(ksrc, ldsK0); gl_lds16(vsrc, ldsV0);
    ksrc += 64 * HD; vsrc += 64;
    compute((const short*)KV[2], (const short*)KV[3]);
    __syncthreads();
  }

  // ------- key-half merge (fixed-max: partials just add) -------
  lsum += __shfl_xor(lsum, 32);       // both g-halves -> full 32-key sum for q=l31
  float* M = (float*)KV;              // 32KB retired staging = merge buffer
  if (kh == 1) {
#pragma unroll
    for (int nt = 0; nt < 2; ++nt)
#pragma unroll
      for (int r = 0; r < 16; ++r) {
        const int idx = nt * 16 + r;
        M[qg * 2048 + lane * 32 + ((idx + lane) & 31)] = oacc[nt][r];
      }
    if (lane < 32) Ls[qg][l31] = lsum;
  }
  __syncthreads();
  if (kh == 0) {
    const float inv = 1.0f / (lsum + Ls[qg][l31]);
    const int b = bh >> 3, h = bh & 7;
    float rl[16];
#pragma unroll
    for (int r = 0; r < 16; ++r)
      rl[r] = __shfl(inv, (r & 3) + 8 * (r >> 2) + 4 * g);
#pragma unroll
    for (int nt = 0; nt < 2; ++nt)
#pragma unroll
      for (int r = 0; r < 16; ++r) {
        const int idx = nt * 16 + r;
        const float val = (oacc[nt][r] +
                           M[qg * 2048 + lane * 32 + ((idx + lane) & 31)]) * rl[r];
        const int n = q0 + qg * 32 + (r & 3) + 8 * (r >> 2) + 4 * g;
        o[((size_t)(b * SEQ + n)) * EMB + h * HD + nt * 32 + l31] = f2bf(val);
      }
  }
}

// ---------------------------------------------------------------- out projection
// v4 (round-10 best): 64x128 tile, BK=32 dbuf, 512 threads (8 waves as 2m x 4f,
// wave tile 32x32, acc[2][2]); grid (128,4) = 512 blocks = 2/CU, LDS 24KB.
__global__ __launch_bounds__(512, 4) void proj_gemm(const short* __restrict__ A,
                                                    const short* __restrict__ W,
                                                    const float* __restrict__ bias,
                                                    float* __restrict__ out) {
  __shared__ __align__(16) short As0[64 * 32];
  __shared__ __align__(16) short Bs0[128 * 32];
  __shared__ __align__(16) short As1[64 * 32];
  __shared__ __align__(16) short Bs1[128 * 32];
  const int tid  = threadIdx.x;
  const int lane = tid & 63, wave = tid >> 6;
  const int wm = wave >> 2, wf = wave & 3;
  const int col = lane & 15, quad = lane >> 4;
  const int m0 = blockIdx.x * 64, f0 = blockIdx.y * 128;

  const int aslot = tid & 255;
  const int arow = aslot >> 2, acb = (aslot & 3) ^ ((aslot >> 3) & 3);
  const short* aSrc = A + (size_t)(m0 + arow) * 512 + acb * 8;
  const int wrow = tid >> 2, wcb = (tid & 3) ^ ((tid >> 3) & 3);
  const short* wSrc = W + (size_t)(f0 + wrow) * 512 + wcb * 8;

  const int rc = (quad ^ ((col >> 1) & 3)) * 8;
  int aOff[2], bOff[2];
#pragma unroll
  for (int i = 0; i < 2; ++i) aOff[i] = (wm * 32 + i * 16 + col) * 32 + rc;
#pragma unroll
  for (int j = 0; j < 2; ++j) bOff[j] = (wf * 32 + j * 16 + col) * 32 + rc;

  f32x4 acc[2][2];
#pragma unroll
  for (int i = 0; i < 2; ++i)
#pragma unroll
    for (int j = 0; j < 2; ++j)
#pragma unroll
      for (int r = 0; r < 4; ++r) acc[i][j][r] = 0.f;

#define PSTAGE(BUFA, BUFB, KS)                                        \
  {                                                                   \
    if (wave < 4) gl_lds16(aSrc + (KS) * 32, (char*)(BUFA) + wave * 1024); \
    gl_lds16(wSrc + (KS) * 32, (char*)(BUFB) + wave * 1024);          \
  }

  auto pcompute = [&](const short* As, const short* Bs) {
    bf16x8 af[2], bw[2];
#pragma unroll
    for (int i = 0; i < 2; ++i) af[i] = *(const bf16x8*)&As[aOff[i]];
#pragma unroll
    for (int j = 0; j < 2; ++j) bw[j] = *(const bf16x8*)&Bs[bOff[j]];
#pragma unroll
    for (int i = 0; i < 2; ++i)
#pragma unroll
      for (int j = 0; j < 2; ++j)
        acc[i][j] = __builtin_amdgcn_mfma_f32_16x16x32_bf16(af[i], bw[j], acc[i][j], 0, 0, 0);
  };

  PSTAGE(As0, Bs0, 0);
  __syncthreads();
  for (int t = 0; t < 16; t += 2) {
    PSTAGE(As1, Bs1, t + 1);
    pcompute(As0, Bs0);
    __syncthreads();
    PSTAGE(As0, Bs0, (t + 2) & 15);   // wrap on last iter (harmless, avoids OOB)
    pcompute(As1, Bs1);
    __syncthreads();
  }
#undef PSTAGE

#pragma unroll
  for (int j = 0; j < 2; ++j) {
    const int f = f0 + wf * 32 + j * 16 + col;
    const float bv = bias[f];
#pragma unroll
    for (int i = 0; i < 2; ++i) {
      const int mbase = m0 + wm * 32 + i * 16 + quad * 4;
#pragma unroll
      for (int r = 0; r < 4; ++r)
        out[(size_t)(mbase + r) * 512 + f] = acc[i][j][r] + bv;
    }
  }
}

// ---------------------------------------------------------------- launch
extern "C" void kernel_launch(void* const* d_in, const int* in_sizes, int n_in,
                              void* d_out, int out_size, void* d_ws, size_t ws_size,
                              hipStream_t stream) {
  (void)in_sizes; (void)n_in; (void)out_size; (void)ws_size;
  const float* x     = (const float*)d_in[0];
  const float* w_qkv = (const float*)d_in[1];
  const float* b_qkv = (const float*)d_in[2];
  const float* w_out = (const float*)d_in[3];
  const float* b_out = (const float*)d_in[4];
  float* out = (float*)d_out;

  char* ws = (char*)d_ws;
  short* xb    = (short*)(ws + 0);         // 8,388,608
  short* wqkvb = (short*)(ws + 8388608);   // 1,572,864
  short* woutb = (short*)(ws + 9961472);   //   524,288
  short* qb    = (short*)(ws + 10485760);  // 8,388,608  (b,h,n,d)  pre-scaled by QSCALE
  short* kb    = (short*)(ws + 18874368);  // 8,388,608  (b,h,n,d)
  short* vtb   = (short*)(ws + 27262976);  // 8,388,608  (b,h,d,n)
  short* ob    = (short*)(ws + 35651584);  // 8,388,608  (b,n,e)

  cast_all<<<5120, 256, 0, stream>>>(x, w_qkv, w_out, xb, wqkvb, woutb);
  qkv_gemm<<<dim3(64, 12), 512, 0, stream>>>(xb, wqkvb, b_qkv, qb, kb, vtb);
  attn_kernel<<<512, 512, 0, stream>>>(qb, kb, vtb, ob);
  proj_gemm<<<dim3(128, 4), 512, 0, stream>>>(ob, woutb, b_out, out);
}